// Round 9
// baseline (345.038 us; speedup 1.0000x reference)
//
#include <hip/hip_runtime.h>
#include <hip/hip_bf16.h>

// EmbeddingLoss — ROUND 9 = DIAGNOSTIC ABLATION (answer still exact).
// The R8 fp8 kernel's main loop is executed 16x (#pragma unroll 1) and the
// epilogue divides acc by 16 (2/16 = 0.125f, exact). Output is unchanged;
// the amplified dispatch isolates main-loop cost f from per-block fixed
// cost o via dur16 = o + 16f (R8 measured o + f ~= 41 us).

#define BN 8192
#define DK 256
#define NT 64                      // BN/128 tiles per dim
#define NBLK (NT * (NT + 1) / 2)   // 2080 upper-tri tiles = 8*260
#define REPS 16

typedef float f32x4 __attribute__((ext_vector_type(4)));

typedef const __attribute__((address_space(1))) void* gas_vp;
typedef __attribute__((address_space(3))) void* las_vp;

// float -> OCP e4m3fn, RTN-even (software; inputs |x| << 448, no NaN/Inf)
static __device__ __forceinline__ unsigned char f2e4m3(float f) {
    unsigned u = __builtin_bit_cast(unsigned, f);
    unsigned s = (u >> 24) & 0x80;
    int e = (int)((u >> 23) & 0xff) - 127;
    unsigned m = u & 0x7fffff;
    if (e < -9) return (unsigned char)s;          // underflow -> +-0
    if (e >= -6) {                                // normal e4m3
        unsigned mant = m >> 20;
        unsigned rest = m & 0xfffff;
        unsigned round = (rest > 0x80000u) || (rest == 0x80000u && (mant & 1));
        unsigned val = ((unsigned)(e + 7) << 3) | mant;
        val += round;                             // carry into exp is correct
        return (unsigned char)(s | val);
    }
    int shift = -6 - e;                           // subnormal, 1..3
    unsigned full = 0x800000u | m;
    unsigned rb = 20 + shift;
    unsigned mant = full >> rb;
    unsigned rest = full & ((1u << rb) - 1);
    unsigned half = 1u << (rb - 1);
    unsigned round = (rest > half) || (rest == half && (mant & 1));
    mant += round;
    return (unsigned char)(s | mant);
}

// ---------------- prep: fp32->fp8 (ws) + fp32 row norms (ws), zero out -----
__global__ __launch_bounds__(256) void embl_prep(
    const float* __restrict__ E, unsigned char* __restrict__ E8,
    float* __restrict__ sq, float* __restrict__ out)
{
    const int lane = threadIdx.x & 63;
    const int wid  = threadIdx.x >> 6;
    const int row  = blockIdx.x * 4 + wid;    // one row per wave
    if (blockIdx.x == 0 && threadIdx.x == 0) *out = 0.0f;
    const float4 v = *(const float4*)(E + row * DK + lane * 4);
    float s = v.x*v.x + v.y*v.y + v.z*v.z + v.w*v.w;
    uchar4 o;
    o.x = f2e4m3(v.x); o.y = f2e4m3(v.y); o.z = f2e4m3(v.z); o.w = f2e4m3(v.w);
    *(uchar4*)(E8 + row * DK + lane * 4) = o;
    #pragma unroll
    for (int off = 32; off > 0; off >>= 1) s += __shfl_xor(s, off, 64);
    if (lane == 0) sq[row] = s;
}

// ---------------- main: R8 structure, main loop x16 (diagnostic) -----------
__global__ __launch_bounds__(256, 4) void embl_gram16(
    const unsigned char* __restrict__ E8, const float* __restrict__ sq,
    const int* __restrict__ lab, float* __restrict__ out)
{
    __shared__ alignas(16) unsigned char As[2][128 * 64];   // 8KB per buf
    __shared__ alignas(16) unsigned char Bs[2][128 * 64];
    __shared__ float wpart[4];

    // XCD-aware chunked swizzle, bijective: 2080 = 8 * 260
    const int bid = (blockIdx.x & 7) * 260 + (blockIdx.x >> 3);
    int t = bid, ti = 0, rl = NT;
    while (t >= rl) { t -= rl; --rl; ++ti; }
    const int tj = ti + t;

    const int tid  = threadIdx.x;
    const int lane = tid & 63;
    const int wid  = tid >> 6;
    const int wr   = wid >> 1;          // 0..1 -> 64-row half
    const int wc   = wid & 1;           // 0..1 -> 64-col half

    const int lcol = lane & 15;         // MFMA frag row/col index
    const int kg   = lane >> 4;         // 0..3 k-group (8B each)
    const int lsw  = lcol & 3;          // read-side XOR key (== row & 3)

    const char* E8c = (const char*)E8;
    const int arow = ti * 128;
    const int brow = tj * 128;

#define STAGE(dst, grow, kt)                                                   \
    {                                                                          \
        _Pragma("unroll")                                                      \
        for (int it_ = 0; it_ < 2; ++it_) {                                    \
            const int c_   = it_ * 256 + tid;   /* 0..511 */                   \
            const int row_ = c_ >> 2;           /* 0..127 */                   \
            const int sch_ = (c_ & 3) ^ (row_ & 3);                            \
            __builtin_amdgcn_global_load_lds(                                  \
                (gas_vp)(E8c + (long)((grow) + row_) * 256 + (kt) * 64 + sch_ * 16), \
                (las_vp)((char*)(dst) + c_ * 16), 16, 0, 0);                   \
        }                                                                      \
    }

#define WAITVM(N)                                                              \
    {                                                                          \
        asm volatile("s_waitcnt vmcnt(" #N ")" ::: "memory");                  \
        __builtin_amdgcn_sched_barrier(0);                                     \
        __builtin_amdgcn_s_barrier();                                          \
        __builtin_amdgcn_sched_barrier(0);                                     \
    }

#define LD8(base, row, ks)                                                     \
    (*(const long*)((const char*)(base) + (long)(row) * 64 +                   \
        ((((ks) * 2 + (kg >> 1)) ^ lsw) * 16) + (kg & 1) * 8))

#define TILE(buf)                                                              \
    {                                                                          \
        long a_[4][2], b_[4][2];                                               \
        _Pragma("unroll")                                                      \
        for (int ks = 0; ks < 2; ++ks) {                                       \
            _Pragma("unroll")                                                  \
            for (int m_ = 0; m_ < 4; ++m_) {                                   \
                a_[m_][ks] = LD8(&As[buf][0], wr * 64 + m_ * 16 + lcol, ks);   \
                b_[m_][ks] = LD8(&Bs[buf][0], wc * 64 + m_ * 16 + lcol, ks);   \
            }                                                                  \
        }                                                                      \
        __builtin_amdgcn_s_setprio(1);                                         \
        _Pragma("unroll")                                                      \
        for (int ks = 0; ks < 2; ++ks)                                         \
        _Pragma("unroll")                                                      \
        for (int m_ = 0; m_ < 4; ++m_)                                         \
        _Pragma("unroll")                                                      \
        for (int n_ = 0; n_ < 4; ++n_)                                         \
            acc[m_][n_] = __builtin_amdgcn_mfma_f32_16x16x32_fp8_fp8(          \
                a_[m_][ks], b_[n_][ks], acc[m_][n_], 0, 0, 0);                 \
        __builtin_amdgcn_s_setprio(0);                                         \
        __builtin_amdgcn_sched_barrier(0);                                     \
        __builtin_amdgcn_s_barrier();   /* all waves done reading buf */       \
        __builtin_amdgcn_sched_barrier(0);                                     \
    }

    f32x4 acc[4][4] = {};

    // ======== DIAGNOSTIC: 16 identical self-contained main-loop passes =====
    #pragma unroll 1
    for (int rep = 0; rep < REPS; ++rep) {
        STAGE(As[0], arow, 0); STAGE(Bs[0], brow, 0);
        STAGE(As[1], arow, 1); STAGE(Bs[1], brow, 1);
        WAITVM(4);                      // t0 landed (t1 in flight)
        TILE(0);
        STAGE(As[0], arow, 2); STAGE(Bs[0], brow, 2);
        WAITVM(4);                      // t1 landed (t2 in flight)
        TILE(1);
        STAGE(As[1], arow, 3); STAGE(Bs[1], brow, 3);
        WAITVM(4);                      // t2 landed (t3 in flight)
        TILE(0);
        WAITVM(0);                      // t3 landed
        TILE(1);
    }

    // ---- epilogue: acc holds 16x gram; 2/16 = 0.125f exact ---------------
    const int gi0 = arow + wr * 64;
    const int gj0 = brow + wc * 64;
    float lsum = 0.0f;

#define EPI(MASKED)                                                            \
    {                                                                          \
        float sqj_[4]; int lj_[4], jj_[4];                                     \
        _Pragma("unroll")                                                      \
        for (int n_ = 0; n_ < 4; ++n_) {                                       \
            jj_[n_] = gj0 + n_ * 16 + lcol;                                    \
            sqj_[n_] = sq[jj_[n_]]; lj_[n_] = lab[jj_[n_]];                    \
        }                                                                      \
        _Pragma("unroll")                                                      \
        for (int m_ = 0; m_ < 4; ++m_) {                                       \
            const int ibase = gi0 + m_ * 16 + kg * 4;                          \
            _Pragma("unroll")                                                  \
            for (int r_ = 0; r_ < 4; ++r_) {                                   \
                const int i_ = ibase + r_;                                     \
                const float sqi_ = sq[i_]; const int li_ = lab[i_];            \
                _Pragma("unroll")                                              \
                for (int n_ = 0; n_ < 4; ++n_) {                               \
                    const float mse_ =                                         \
                        (sqi_ + sqj_[n_] - 0.125f * acc[m_][n_][r_]) *         \
                        (1.0f / 256.0f);                                       \
                    float v_ = (li_ == lj_[n_]) ? mse_                         \
                                                : fmaxf(0.0f, 1.0f - mse_);    \
                    if (MASKED && i_ >= jj_[n_]) v_ = 0.0f;                    \
                    lsum += v_;                                                \
                }                                                              \
            }                                                                  \
        }                                                                      \
    }

    if (ti == tj) { EPI(1) } else { EPI(0) }

    #pragma unroll
    for (int off = 32; off > 0; off >>= 1) lsum += __shfl_xor(lsum, off, 64);
    if (lane == 0) wpart[wid] = lsum;
    __syncthreads();
    if (tid == 0) {
        const float scale = 1.0f / ((float)BN * (float)(BN - 1));
        atomicAdd(out, (wpart[0] + wpart[1] + wpart[2] + wpart[3]) * scale);
    }
}

extern "C" void kernel_launch(void* const* d_in, const int* in_sizes, int n_in,
                              void* d_out, int out_size, void* d_ws, size_t ws_size,
                              hipStream_t stream) {
    const float* E   = (const float*)d_in[0];
    const int*   lab = (const int*)d_in[1];
    float*       out = (float*)d_out;

    unsigned char* E8 = (unsigned char*)d_ws;                       // 2 MiB
    float*         sq = (float*)((char*)d_ws + (size_t)BN * DK);    // 32 KiB

    embl_prep<<<BN / 4, 256, 0, stream>>>(E, E8, sq, out);
    embl_gram16<<<NBLK, 256, 0, stream>>>(E8, sq, lab, out);
}

// Round 10
// 82.553 us; speedup vs baseline: 4.1796x; 4.1796x over previous
//
#include <hip/hip_runtime.h>
#include <hip/hip_bf16.h>

// EmbeddingLoss: loss = sum_{i<j} [ same ? mse : max(0,1-mse) ] / (B*(B-1))
// Round 10 (from R9 ablation: f=18.3us w/ 1e8 LDS conflicts, o=22.7us w/
// single-address atomic):
//  * BK=128 fp8, k-permuted storage -> ds_read_b128 frags, row stride 128B,
//    chunk^=row&7 (the empirically-clean R4 geometry). Permutation applied
//    to BOTH operands in prep => gram unchanged.
//  * partials[bid] + 1-block reduce kernel (no same-address atomics).
//  * 32KB LDS (A+B, no dbuf), 4 blocks/CU, 3 barrier points per block.

#define BN 8192
#define DK 256
#define NT 64                      // BN/128 tiles per dim
#define NBLK (NT * (NT + 1) / 2)   // 2080 upper-tri tiles = 8*260

typedef float f32x4 __attribute__((ext_vector_type(4)));
typedef long  lx2   __attribute__((ext_vector_type(2)));

typedef const __attribute__((address_space(1))) void* gas_vp;
typedef __attribute__((address_space(3))) void* las_vp;

// float -> OCP e4m3fn, RTN-even (software; inputs |x| << 448, no NaN/Inf)
static __device__ __forceinline__ unsigned char f2e4m3(float f) {
    unsigned u = __builtin_bit_cast(unsigned, f);
    unsigned s = (u >> 24) & 0x80;
    int e = (int)((u >> 23) & 0xff) - 127;
    unsigned m = u & 0x7fffff;
    if (e < -9) return (unsigned char)s;          // underflow -> +-0
    if (e >= -6) {                                // normal e4m3
        unsigned mant = m >> 20;
        unsigned rest = m & 0xfffff;
        unsigned round = (rest > 0x80000u) || (rest == 0x80000u && (mant & 1));
        unsigned val = ((unsigned)(e + 7) << 3) | mant;
        val += round;
        return (unsigned char)(s | val);
    }
    int shift = -6 - e;                           // subnormal, 1..3
    unsigned full = 0x800000u | m;
    unsigned rb = 20 + shift;
    unsigned mant = full >> rb;
    unsigned rest = full & ((1u << rb) - 1);
    unsigned half = 1u << (rb - 1);
    unsigned round = (rest > half) || (rest == half && (mant & 1));
    mant += round;
    return (unsigned char)(s | mant);
}

// ---- prep: fp32 -> fp8 with k-permutation + fp32 row norms ----------------
// Per K-half h (128 fp8): LDS/global chunk c(0..7),p(0..1) holds k-segment
// s = (c>>2)*2+p, kg-slice = c&3:  dst = h*128 + c*16 + p*8 + (k&7..)
__global__ __launch_bounds__(256) void embl_prep(
    const float* __restrict__ E, unsigned char* __restrict__ E8,
    float* __restrict__ sq)
{
    const int lane = threadIdx.x & 63;
    const int wid  = threadIdx.x >> 6;
    const int row  = blockIdx.x * 4 + wid;    // one row per wave
    const float4 v = *(const float4*)(E + row * DK + lane * 4);
    float s = v.x*v.x + v.y*v.y + v.z*v.z + v.w*v.w;
    uchar4 o;
    o.x = f2e4m3(v.x); o.y = f2e4m3(v.y); o.z = f2e4m3(v.z); o.w = f2e4m3(v.w);
    // lane covers k = lane*4 .. +4; decompose for permuted destination
    const int h   = lane >> 5;            // K-half
    const int s_  = (lane >> 3) & 3;      // 32-wide k-segment (= MFMA ks)
    const int kg_ = (lane >> 1) & 3;      // 8-wide lane-group slice
    const int b4  = (lane & 1) * 4;       // 4B within the 8B slice
    const int c_  = ((s_ >> 1) << 2) | kg_;
    const int p_  = s_ & 1;
    *(uchar4*)(E8 + row * 256 + h * 128 + c_ * 16 + p_ * 8 + b4) = o;
    #pragma unroll
    for (int off = 32; off > 0; off >>= 1) s += __shfl_xor(s, off, 64);
    if (lane == 0) sq[row] = s;
}

// ---- main: 128x128 fp8 gram tile, BK=128, b128 frag reads -----------------
__global__ __launch_bounds__(256, 4) void embl_gram(
    const unsigned char* __restrict__ E8, const float* __restrict__ sq,
    const int* __restrict__ lab, float* __restrict__ partials)
{
    __shared__ alignas(16) unsigned char As[128 * 128];   // 16KB
    __shared__ alignas(16) unsigned char Bs[128 * 128];   // 16KB
    __shared__ float wpart[4];

    // XCD-aware chunked swizzle, bijective: 2080 = 8 * 260
    const int bid = (blockIdx.x & 7) * 260 + (blockIdx.x >> 3);
    int t = bid, ti = 0, rl = NT;
    while (t >= rl) { t -= rl; --rl; ++ti; }
    const int tj = ti + t;

    const int tid  = threadIdx.x;
    const int lane = tid & 63;
    const int wid  = tid >> 6;
    const int wr   = wid >> 1;          // 0..1 -> 64-row half
    const int wc   = wid & 1;           // 0..1 -> 64-col half

    const int lcol = lane & 15;         // MFMA frag row index
    const int kg   = lane >> 4;         // 0..3 k lane-group
    const int lk7  = lcol & 7;          // read-side XOR key (== row&7)

    const char* E8c = (const char*)E8;
    const int arow = ti * 128;
    const int brow = tj * 128;

    // stage one op K-tile (128 rows x 128B = 16KB = 1024 chunks): 4 loads/thr
#define STAGE(dst, grow, kt)                                                   \
    {                                                                          \
        _Pragma("unroll")                                                      \
        for (int it_ = 0; it_ < 4; ++it_) {                                    \
            const int c_   = it_ * 256 + tid;   /* 0..1023 */                  \
            const int row_ = c_ >> 3;           /* 0..127  */                  \
            const int sch_ = (c_ & 7) ^ (row_ & 7);                            \
            __builtin_amdgcn_global_load_lds(                                  \
                (gas_vp)(E8c + (long)((grow) + row_) * 256 + (kt) * 128 + sch_ * 16), \
                (las_vp)((char*)(dst) + c_ * 16), 16, 0, 0);                   \
        }                                                                      \
    }

#define WAITVM(N)                                                              \
    {                                                                          \
        asm volatile("s_waitcnt vmcnt(" #N ")" ::: "memory");                  \
        __builtin_amdgcn_sched_barrier(0);                                     \
        __builtin_amdgcn_s_barrier();                                          \
        __builtin_amdgcn_sched_barrier(0);                                     \
    }

    // b128 fragment read: row stride 128B, chunk = (p*4+kg) ^ (row&7).
    // Returns ulong2: [0] = ks (2p), [1] = ks (2p+1) fragment (8B each).
#define LDF(base, R0, p)                                                       \
    (*(const lx2*)((const char*)(base) + (long)((R0) + lcol) * 128 +           \
        ((((p) * 4 + kg) ^ lk7) * 16)))

    // half-tile: pass p covers MFMA ks = 2p, 2p+1  (8 b128 reads, 32 MFMA)
#define HALF(p)                                                                \
    {                                                                          \
        lx2 a_[4], b_[4];                                                      \
        _Pragma("unroll")                                                      \
        for (int m_ = 0; m_ < 4; ++m_) {                                       \
            a_[m_] = LDF(As, wr * 64 + m_ * 16, p);                            \
            b_[m_] = LDF(Bs, wc * 64 + m_ * 16, p);                            \
        }                                                                      \
        __builtin_amdgcn_s_setprio(1);                                         \
        _Pragma("unroll")                                                      \
        for (int m_ = 0; m_ < 4; ++m_)                                         \
        _Pragma("unroll")                                                      \
        for (int n_ = 0; n_ < 4; ++n_)                                         \
            acc[m_][n_] = __builtin_amdgcn_mfma_f32_16x16x32_fp8_fp8(          \
                a_[m_][0], b_[n_][0], acc[m_][n_], 0, 0, 0);                   \
        _Pragma("unroll")                                                      \
        for (int m_ = 0; m_ < 4; ++m_)                                         \
        _Pragma("unroll")                                                      \
        for (int n_ = 0; n_ < 4; ++n_)                                         \
            acc[m_][n_] = __builtin_amdgcn_mfma_f32_16x16x32_fp8_fp8(          \
                a_[m_][1], b_[n_][1], acc[m_][n_], 0, 0, 0);                   \
        __builtin_amdgcn_s_setprio(0);                                         \
    }

    f32x4 acc[4][4] = {};

    // K-tile 0
    STAGE(As, arow, 0); STAGE(Bs, brow, 0);
    WAITVM(0);                          // t0 landed, all waves
    HALF(0); HALF(1);
    __builtin_amdgcn_sched_barrier(0);
    __builtin_amdgcn_s_barrier();       // all waves done reading tile 0
    __builtin_amdgcn_sched_barrier(0);
    // K-tile 1
    STAGE(As, arow, 1); STAGE(Bs, brow, 1);
    WAITVM(0);
    HALF(0); HALF(1);

    // ---- epilogue: C/D layout col=lane&15, row=(lane>>4)*4+reg ------------
    const int gi0 = arow + wr * 64;
    const int gj0 = brow + wc * 64;
    float lsum = 0.0f;

#define EPI(MASKED)                                                            \
    {                                                                          \
        float sqj_[4]; int lj_[4], jj_[4];                                     \
        _Pragma("unroll")                                                      \
        for (int n_ = 0; n_ < 4; ++n_) {                                       \
            jj_[n_] = gj0 + n_ * 16 + lcol;                                    \
            sqj_[n_] = sq[jj_[n_]]; lj_[n_] = lab[jj_[n_]];                    \
        }                                                                      \
        _Pragma("unroll")                                                      \
        for (int m_ = 0; m_ < 4; ++m_) {                                       \
            const int ibase = gi0 + m_ * 16 + kg * 4;                          \
            _Pragma("unroll")                                                  \
            for (int r_ = 0; r_ < 4; ++r_) {                                   \
                const int i_ = ibase + r_;                                     \
                const float sqi_ = sq[i_]; const int li_ = lab[i_];            \
                _Pragma("unroll")                                              \
                for (int n_ = 0; n_ < 4; ++n_) {                               \
                    const float mse_ =                                         \
                        (sqi_ + sqj_[n_] - 2.0f * acc[m_][n_][r_]) *           \
                        (1.0f / 256.0f);                                       \
                    float v_ = (li_ == lj_[n_]) ? mse_                         \
                                                : fmaxf(0.0f, 1.0f - mse_);    \
                    if (MASKED && i_ >= jj_[n_]) v_ = 0.0f;                    \
                    lsum += v_;                                                \
                }                                                              \
            }                                                                  \
        }                                                                      \
    }

    if (ti == tj) { EPI(1) } else { EPI(0) }

    #pragma unroll
    for (int off = 32; off > 0; off >>= 1) lsum += __shfl_xor(lsum, off, 64);
    if (lane == 0) wpart[wid] = lsum;
    __syncthreads();
    if (tid == 0)
        partials[blockIdx.x] = wpart[0] + wpart[1] + wpart[2] + wpart[3];
}

// ---- final reduce: 2080 partials -> scaled scalar -------------------------
__global__ __launch_bounds__(1024) void embl_reduce(
    const float* __restrict__ partials, float* __restrict__ out)
{
    __shared__ float w[16];
    const int tid  = threadIdx.x;
    const int lane = tid & 63;
    float s = partials[tid] + partials[tid + 1024];
    if (tid < NBLK - 2048) s += partials[tid + 2048];
    #pragma unroll
    for (int off = 32; off > 0; off >>= 1) s += __shfl_xor(s, off, 64);
    if (lane == 0) w[tid >> 6] = s;
    __syncthreads();
    if (tid == 0) {
        float t = 0.0f;
        #pragma unroll
        for (int i = 0; i < 16; ++i) t += w[i];
        const float scale = 1.0f / ((float)BN * (float)(BN - 1));
        *out = t * scale;
    }
}

extern "C" void kernel_launch(void* const* d_in, const int* in_sizes, int n_in,
                              void* d_out, int out_size, void* d_ws, size_t ws_size,
                              hipStream_t stream) {
    const float* E   = (const float*)d_in[0];
    const int*   lab = (const int*)d_in[1];
    float*       out = (float*)d_out;

    unsigned char* E8 = (unsigned char*)d_ws;                             // 2 MiB
    float*         sq = (float*)((char*)d_ws + (size_t)BN * DK);          // 32 KiB
    float*   partials = (float*)((char*)d_ws + (size_t)BN * DK + BN * 4); // 8.3 KB

    embl_prep<<<BN / 4, 256, 0, stream>>>(E, E8, sq);
    embl_gram<<<NBLK, 256, 0, stream>>>(E8, sq, lab, partials);
    embl_reduce<<<1, 1024, 0, stream>>>(partials, out);
}